// Round 1
// baseline (141.942 us; speedup 1.0000x reference)
//
#include <hip/hip_runtime.h>
#include <math.h>

// Problem dims (fixed by setup_inputs)
constexpr int B = 4, C = 256, H = 128, W = 128, N = 4096, A = 5;
constexpr int HWs = H * W;
constexpr float AROUND_R = 0.1f;

__device__ __forceinline__ float wave_reduce_sum(float v) {
    #pragma unroll
    for (int off = 32; off > 0; off >>= 1)
        v += __shfl_xor(v, off);
    return v;
}

// Transpose one image set [B,C,H*W] -> [B,H*W,C], LDS-tiled.
__global__ __launch_bounds__(256) void transpose_chw_hwc(const float* __restrict__ in,
                                                         float* __restrict__ out) {
    constexpr int TILE = 32;
    __shared__ float t[TILE][C + 1];   // +1 pad: phase-1 store stride 257 -> conflict-free
    const int tilesPerB = HWs / TILE;  // 512
    int bx = blockIdx.x;
    int b  = bx / tilesPerB;
    int hw0 = (bx % tilesPerB) * TILE;
    int tid  = threadIdx.x;
    int hw_l = tid & 31;
    int cg   = tid >> 5;  // 0..7

    const float* src = in + (size_t)b * C * HWs;
    #pragma unroll
    for (int ci = 0; ci < C / 8; ++ci) {
        int c = ci * 8 + cg;
        t[hw_l][c] = src[(size_t)c * HWs + hw0 + hw_l];  // coalesced along hw
    }
    __syncthreads();
    float* dst = out + ((size_t)b * HWs + hw0) * C;
    #pragma unroll
    for (int hwi = 0; hwi < TILE; ++hwi) {
        dst[(size_t)hwi * C + tid] = t[hwi][tid];        // coalesced along c
    }
}

// One wave per (b,n) point. Lane l owns channels 4l..4l+3.
template <bool HWC>
__global__ __launch_bounds__(256) void soft_align_kernel(
    const float* __restrict__ x1,  // HWC ? [B,HW,C] : [B,C,HW]
    const float* __restrict__ pe,  // same layout as x1
    const float* __restrict__ pf,  // [B,N,C]
    const float* __restrict__ pts, // [B,N,2]
    const float* __restrict__ ao,  // [B,A,N,2]
    float* __restrict__ out)       // [B,N,C]
{
    int tid  = threadIdx.x;
    int lane = tid & 63;
    int wave = tid >> 6;
    int p = blockIdx.x * 4 + wave;
    if (p >= B * N) return;
    int b = p / N, n = p % N;
    const int c0 = lane * 4;

    // rep = points_feature[b,n,:]
    const float* pf_p = pf + ((size_t)b * N + n) * C;
    float4 rep = *reinterpret_cast<const float4*>(pf_p + c0);
    float na2 = rep.x * rep.x + rep.y * rep.y + rep.z * rep.z + rep.w * rep.w;
    na2 = wave_reduce_sum(na2);
    float na = fmaxf(sqrtf(na2), 1e-8f);

    float gx0 = pts[((size_t)b * N + n) * 2 + 0];
    float gy0 = pts[((size_t)b * N + n) * 2 + 1];

    float4 emb[A];
    float  sim[A];

    #pragma unroll
    for (int a = 0; a < A; ++a) {
        float aox = ao[(((size_t)b * A + a) * N + n) * 2 + 0];
        float aoy = ao[(((size_t)b * A + a) * N + n) * 2 + 1];
        float gx = fminf(fmaxf(gx0 + (aox * 2.0f - 0.5f) * (2.0f * AROUND_R), -1.0f), 1.0f);
        float gy = fminf(fmaxf(gy0 + (aoy * 2.0f - 0.5f) * (2.0f * AROUND_R), -1.0f), 1.0f);
        float x = (gx + 1.0f) * (W * 0.5f) - 0.5f;
        float y = (gy + 1.0f) * (H * 0.5f) - 0.5f;
        float fx0 = floorf(x), fy0 = floorf(y);
        float wx1 = x - fx0, wy1 = y - fy0;
        float wx0 = 1.0f - wx1, wy0 = 1.0f - wy1;
        int ix0 = (int)fx0, iy0 = (int)fy0;
        int ix1 = ix0 + 1, iy1 = iy0 + 1;
        bool vx0 = (ix0 >= 0) && (ix0 < W);
        bool vx1 = (ix1 >= 0) && (ix1 < W);
        bool vy0 = (iy0 >= 0) && (iy0 < H);
        bool vy1 = (iy1 >= 0) && (iy1 < H);
        int cx0 = min(max(ix0, 0), W - 1), cx1 = min(max(ix1, 0), W - 1);
        int cy0 = min(max(iy0, 0), H - 1), cy1 = min(max(iy1, 0), H - 1);

        int   idxs[4] = {cy0 * W + cx0, cy0 * W + cx1, cy1 * W + cx0, cy1 * W + cx1};
        float wgt[4]  = {wx0 * wy0, wx1 * wy0, wx0 * wy1, wx1 * wy1};
        bool  vld[4]  = {vx0 && vy0, vx1 && vy0, vx0 && vy1, vx1 && vy1};

        float4 feat = make_float4(0.f, 0.f, 0.f, 0.f);
        float4 em   = make_float4(0.f, 0.f, 0.f, 0.f);
        #pragma unroll
        for (int k = 0; k < 4; ++k) {
            if (vld[k]) {
                float4 vx4, ve4;
                if (HWC) {
                    size_t base = ((size_t)b * HWs + idxs[k]) * C + c0;
                    vx4 = *reinterpret_cast<const float4*>(x1 + base);
                    ve4 = *reinterpret_cast<const float4*>(pe + base);
                } else {
                    size_t base = ((size_t)b * C + c0) * (size_t)HWs + idxs[k];
                    vx4 = make_float4(x1[base], x1[base + HWs], x1[base + 2 * (size_t)HWs], x1[base + 3 * (size_t)HWs]);
                    ve4 = make_float4(pe[base], pe[base + HWs], pe[base + 2 * (size_t)HWs], pe[base + 3 * (size_t)HWs]);
                }
                float wk = wgt[k];
                feat.x += wk * vx4.x; feat.y += wk * vx4.y; feat.z += wk * vx4.z; feat.w += wk * vx4.w;
                em.x   += wk * ve4.x; em.y   += wk * ve4.y; em.z   += wk * ve4.z; em.w   += wk * ve4.w;
            }
        }
        float dotv = rep.x * feat.x + rep.y * feat.y + rep.z * feat.z + rep.w * feat.w;
        float nb2  = feat.x * feat.x + feat.y * feat.y + feat.z * feat.z + feat.w * feat.w;
        dotv = wave_reduce_sum(dotv);
        nb2  = wave_reduce_sum(nb2);
        float nb = fmaxf(sqrtf(nb2), 1e-8f);
        sim[a] = dotv / (na * nb);
        emb[a] = em;
    }

    // softmax over A (values uniform across lanes)
    float m = sim[0];
    #pragma unroll
    for (int a = 1; a < A; ++a) m = fmaxf(m, sim[a]);
    float e[A], s = 0.f;
    #pragma unroll
    for (int a = 0; a < A; ++a) { e[a] = expf(sim[a] - m); s += e[a]; }
    float inv = 1.0f / s;

    float4 acc = make_float4(0.f, 0.f, 0.f, 0.f);
    #pragma unroll
    for (int a = 0; a < A; ++a) {
        float wa = e[a] * inv;
        acc.x += wa * emb[a].x; acc.y += wa * emb[a].y;
        acc.z += wa * emb[a].z; acc.w += wa * emb[a].w;
    }
    float4 o = make_float4(rep.x + acc.x, rep.y + acc.y, rep.z + acc.z, rep.w + acc.w);
    *reinterpret_cast<float4*>(out + ((size_t)b * N + n) * C + c0) = o;
}

extern "C" void kernel_launch(void* const* d_in, const int* in_sizes, int n_in,
                              void* d_out, int out_size, void* d_ws, size_t ws_size,
                              hipStream_t stream) {
    const float* x1  = (const float*)d_in[0];
    const float* pf  = (const float*)d_in[1];
    const float* pts = (const float*)d_in[2];
    const float* pe  = (const float*)d_in[3];
    const float* ao  = (const float*)d_in[4];
    float* out = (float*)d_out;

    const size_t imgElems = (size_t)B * HWs * C;           // 16,777,216
    const size_t need     = 2 * imgElems * sizeof(float);  // 134 MB

    if (ws_size >= need) {
        float* x1t = (float*)d_ws;
        float* pet = x1t + imgElems;
        int tblocks = B * (HWs / 32);  // 2048
        transpose_chw_hwc<<<tblocks, 256, 0, stream>>>(x1, x1t);
        transpose_chw_hwc<<<tblocks, 256, 0, stream>>>(pe, pet);
        soft_align_kernel<true><<<(B * N) / 4, 256, 0, stream>>>(x1t, pet, pf, pts, ao, out);
    } else {
        soft_align_kernel<false><<<(B * N) / 4, 256, 0, stream>>>(x1, pe, pf, pts, ao, out);
    }
}

// Round 2
// 83.333 us; speedup vs baseline: 1.7033x; 1.7033x over previous
//
#include <hip/hip_runtime.h>
#include <hip/hip_bf16.h>
#include <math.h>

// Problem dims (fixed by setup_inputs)
constexpr int B = 4, C = 256, H = 128, W = 128, N = 4096, A = 5;
constexpr int HWs = H * W;
constexpr float AROUND_R = 0.1f;

__device__ __forceinline__ float wave_reduce_sum(float v) {
    #pragma unroll
    for (int off = 32; off > 0; off >>= 1)
        v += __shfl_xor(v, off);
    return v;
}

__device__ __forceinline__ float bf2f(unsigned short u) {
    union { unsigned int i; float f; } x;
    x.i = ((unsigned int)u) << 16;
    return x.f;
}

// Transpose one image [B,C,HW] f32 -> interleaved [B,HW,2,C] bf16 (img = 0 or 1).
__global__ __launch_bounds__(256) void transpose_conv(const float* __restrict__ in,
                                                      __hip_bfloat16* __restrict__ out,
                                                      int img) {
    constexpr int TILE = 32;
    __shared__ float t[TILE][C + 1];   // stride 257 -> conflict-free both phases
    const int tilesPerB = HWs / TILE;  // 512
    int bx = blockIdx.x;
    int b  = bx / tilesPerB;
    int hw0 = (bx % tilesPerB) * TILE;
    int tid  = threadIdx.x;
    int hw_l = tid & 31;
    int cg   = tid >> 5;  // 0..7

    const float* src = in + (size_t)b * C * HWs;
    #pragma unroll
    for (int ci = 0; ci < C / 8; ++ci) {
        int c = ci * 8 + cg;
        t[hw_l][c] = src[(size_t)c * HWs + hw0 + hw_l];  // coalesced along hw
    }
    __syncthreads();
    __hip_bfloat16* dst = out + (((size_t)b * HWs + hw0) * 2 + img) * C;
    #pragma unroll
    for (int hwi = 0; hwi < TILE; ++hwi) {
        dst[(size_t)hwi * 2 * C + tid] = __float2bfloat16(t[hwi][tid]);  // 512B contiguous/row
    }
}

// One wave per (b,n) point. Lane l owns channels 4l..4l+3 of each image.
__global__ __launch_bounds__(256) void soft_align_bf16(
    const __hip_bfloat16* __restrict__ imgs, // [B,HW,2,C] bf16: per pixel, x1[0..255], pe[0..255]
    const float* __restrict__ pf,            // [B,N,C]
    const float* __restrict__ pts,           // [B,N,2]
    const float* __restrict__ ao,            // [B,A,N,2]
    float* __restrict__ out)                 // [B,N,C]
{
    int tid  = threadIdx.x;
    int lane = tid & 63;
    int wave = tid >> 6;
    int p = blockIdx.x * 4 + wave;
    int b = p / N, n = p % N;

    // rep = points_feature[b,n,:]
    const float* pf_p = pf + ((size_t)b * N + n) * C;
    float4 rep = *reinterpret_cast<const float4*>(pf_p + lane * 4);
    float na2 = rep.x * rep.x + rep.y * rep.y + rep.z * rep.z + rep.w * rep.w;
    na2 = wave_reduce_sum(na2);
    float na = fmaxf(sqrtf(na2), 1e-8f);

    float gx0 = pts[((size_t)b * N + n) * 2 + 0];
    float gy0 = pts[((size_t)b * N + n) * 2 + 1];

    float4 emb[A];
    float  sim[A];

    #pragma unroll
    for (int a = 0; a < A; ++a) {
        float aox = ao[(((size_t)b * A + a) * N + n) * 2 + 0];
        float aoy = ao[(((size_t)b * A + a) * N + n) * 2 + 1];
        float gx = fminf(fmaxf(gx0 + (aox * 2.0f - 0.5f) * (2.0f * AROUND_R), -1.0f), 1.0f);
        float gy = fminf(fmaxf(gy0 + (aoy * 2.0f - 0.5f) * (2.0f * AROUND_R), -1.0f), 1.0f);
        float x = (gx + 1.0f) * (W * 0.5f) - 0.5f;
        float y = (gy + 1.0f) * (H * 0.5f) - 0.5f;
        float fx0 = floorf(x), fy0 = floorf(y);
        float wx1 = x - fx0, wy1 = y - fy0;
        float wx0 = 1.0f - wx1, wy0 = 1.0f - wy1;
        int ix0 = (int)fx0, iy0 = (int)fy0;
        int ix1 = ix0 + 1, iy1 = iy0 + 1;
        bool vx0 = (ix0 >= 0) && (ix0 < W);
        bool vx1 = (ix1 >= 0) && (ix1 < W);
        bool vy0 = (iy0 >= 0) && (iy0 < H);
        bool vy1 = (iy1 >= 0) && (iy1 < H);
        int cx0 = min(max(ix0, 0), W - 1), cx1 = min(max(ix1, 0), W - 1);
        int cy0 = min(max(iy0, 0), H - 1), cy1 = min(max(iy1, 0), H - 1);

        int   idxs[4] = {cy0 * W + cx0, cy0 * W + cx1, cy1 * W + cx0, cy1 * W + cx1};
        float wgt[4]  = {wx0 * wy0, wx1 * wy0, wx0 * wy1, wx1 * wy1};
        bool  vld[4]  = {vx0 && vy0, vx1 && vy0, vx0 && vy1, vx1 && vy1};

        float4 feat = make_float4(0.f, 0.f, 0.f, 0.f);
        float4 em   = make_float4(0.f, 0.f, 0.f, 0.f);
        #pragma unroll
        for (int k = 0; k < 4; ++k) {
            if (vld[k]) {
                // per-pixel block: 2*C bf16 = 1024 B = 128 ushort4
                const ushort4* px = reinterpret_cast<const ushort4*>(
                    imgs + ((size_t)b * HWs + idxs[k]) * (2 * C));
                ushort4 xv = px[lane];       // x1 channels 4l..4l+3
                ushort4 ev = px[64 + lane];  // pe channels 4l..4l+3
                float wk = wgt[k];
                feat.x += wk * bf2f(xv.x); feat.y += wk * bf2f(xv.y);
                feat.z += wk * bf2f(xv.z); feat.w += wk * bf2f(xv.w);
                em.x   += wk * bf2f(ev.x); em.y   += wk * bf2f(ev.y);
                em.z   += wk * bf2f(ev.z); em.w   += wk * bf2f(ev.w);
            }
        }
        float dotv = rep.x * feat.x + rep.y * feat.y + rep.z * feat.z + rep.w * feat.w;
        float nb2  = feat.x * feat.x + feat.y * feat.y + feat.z * feat.z + feat.w * feat.w;
        dotv = wave_reduce_sum(dotv);
        nb2  = wave_reduce_sum(nb2);
        float nb = fmaxf(sqrtf(nb2), 1e-8f);
        sim[a] = dotv / (na * nb);
        emb[a] = em;
    }

    // softmax over A (values uniform across lanes)
    float m = sim[0];
    #pragma unroll
    for (int a = 1; a < A; ++a) m = fmaxf(m, sim[a]);
    float e[A], s = 0.f;
    #pragma unroll
    for (int a = 0; a < A; ++a) { e[a] = expf(sim[a] - m); s += e[a]; }
    float inv = 1.0f / s;

    float4 acc = make_float4(0.f, 0.f, 0.f, 0.f);
    #pragma unroll
    for (int a = 0; a < A; ++a) {
        float wa = e[a] * inv;
        acc.x += wa * emb[a].x; acc.y += wa * emb[a].y;
        acc.z += wa * emb[a].z; acc.w += wa * emb[a].w;
    }
    float4 o = make_float4(rep.x + acc.x, rep.y + acc.y, rep.z + acc.z, rep.w + acc.w);
    *reinterpret_cast<float4*>(out + ((size_t)b * N + n) * C + lane * 4) = o;
}

extern "C" void kernel_launch(void* const* d_in, const int* in_sizes, int n_in,
                              void* d_out, int out_size, void* d_ws, size_t ws_size,
                              hipStream_t stream) {
    const float* x1  = (const float*)d_in[0];
    const float* pf  = (const float*)d_in[1];
    const float* pts = (const float*)d_in[2];
    const float* pe  = (const float*)d_in[3];
    const float* ao  = (const float*)d_in[4];
    float* out = (float*)d_out;

    __hip_bfloat16* imgs = (__hip_bfloat16*)d_ws;  // [B,HW,2,C] bf16 = 64 MiB

    int tblocks = B * (HWs / 32);  // 2048
    transpose_conv<<<tblocks, 256, 0, stream>>>(x1, imgs, 0);
    transpose_conv<<<tblocks, 256, 0, stream>>>(pe, imgs, 1);
    soft_align_bf16<<<(B * N) / 4, 256, 0, stream>>>(imgs, pf, pts, ao, out);
}

// Round 3
// 81.494 us; speedup vs baseline: 1.7418x; 1.0226x over previous
//
#include <hip/hip_runtime.h>
#include <hip/hip_bf16.h>
#include <math.h>

// Problem dims (fixed by setup_inputs)
constexpr int B = 4, C = 256, H = 128, W = 128, N = 4096, A = 5;
constexpr int HWs = H * W;
constexpr float AROUND_R = 0.1f;

__device__ __forceinline__ float ulo(unsigned u) {
    union { unsigned i; float f; } x; x.i = u << 16; return x.f;
}
__device__ __forceinline__ float uhi(unsigned u) {
    union { unsigned i; float f; } x; x.i = u & 0xffff0000u; return x.f;
}
__device__ __forceinline__ float reduce32(float v) {
    #pragma unroll
    for (int off = 16; off > 0; off >>= 1)
        v += __shfl_xor(v, off);
    return v;
}

// Fused transpose+convert: two [B,C,HW] f32 images -> [B,HW,2C] bf16
// (per pixel: x1 channels 0..255, then pe channels 0..255).
__global__ __launch_bounds__(256) void transpose_conv2(const float* __restrict__ x1,
                                                       const float* __restrict__ pe,
                                                       __hip_bfloat16* __restrict__ outimg) {
    constexpr int TILE = 32;
    __shared__ float t[TILE][C + 1];   // stride 257: conflict-free both phases
    const int tilesPerB = HWs / TILE;  // 512
    int bx  = blockIdx.x;
    int img = bx >> 11;                // 2048 blocks per image
    int r   = bx & 2047;
    int b   = r / tilesPerB;
    int hw0 = (r % tilesPerB) * TILE;
    int tid = threadIdx.x, hw_l = tid & 31, cg = tid >> 5;

    const float* src = (img ? pe : x1) + (size_t)b * C * HWs;
    #pragma unroll
    for (int ci = 0; ci < C / 8; ++ci) {
        int c = ci * 8 + cg;
        t[hw_l][c] = src[(size_t)c * HWs + hw0 + hw_l];  // coalesced along hw
    }
    __syncthreads();
    __hip_bfloat16* dst = outimg + ((size_t)b * HWs + hw0) * (2 * C) + img * C;
    #pragma unroll
    for (int hwi = 0; hwi < TILE; ++hwi) {
        dst[(size_t)hwi * 2 * C + tid] = __float2bfloat16(t[hwi][tid]);
    }
}

// One wave per point. Lanes 0-31: x1 channels (8/lane); lanes 32-63: pe channels.
__global__ __launch_bounds__(256) void soft_align_v3(
    const ushort* __restrict__ imgs,  // [B,HW,2C] bf16
    const float* __restrict__ pf,     // [B,N,C]
    const float* __restrict__ pts,    // [B,N,2]
    const float* __restrict__ ao,     // [B,A,N,2]
    float* __restrict__ out)          // [B,N,C]
{
    int tid = threadIdx.x, lane = tid & 63, wave = tid >> 6;
    int p = blockIdx.x * 4 + wave;
    int b = p >> 12, n = p & (N - 1);
    int cl = lane & 31;                // channel group: channels 8cl..8cl+7
    bool upper = lane >= 32;           // pe half

    size_t pn = (size_t)b * N + n;
    float gx0 = pts[pn * 2 + 0];
    float gy0 = pts[pn * 2 + 1];

    // --- per-sample corner indices + masked weights (wave-uniform -> SGPR) ---
    int   sidx[A][4];
    float swgt[A][4];
    #pragma unroll
    for (int a = 0; a < A; ++a) {
        float aox = ao[(((size_t)b * A + a) * N + n) * 2 + 0];
        float aoy = ao[(((size_t)b * A + a) * N + n) * 2 + 1];
        float gx = fminf(fmaxf(gx0 + (aox * 2.0f - 0.5f) * (2.0f * AROUND_R), -1.0f), 1.0f);
        float gy = fminf(fmaxf(gy0 + (aoy * 2.0f - 0.5f) * (2.0f * AROUND_R), -1.0f), 1.0f);
        float x = (gx + 1.0f) * (W * 0.5f) - 0.5f;
        float y = (gy + 1.0f) * (H * 0.5f) - 0.5f;
        float fx0 = floorf(x), fy0 = floorf(y);
        float wx1 = x - fx0, wy1 = y - fy0;
        float wx0 = 1.0f - wx1, wy0 = 1.0f - wy1;
        int ix0 = (int)fx0, iy0 = (int)fy0, ix1 = ix0 + 1, iy1 = iy0 + 1;
        bool vx0 = (ix0 >= 0) & (ix0 < W), vx1 = (ix1 >= 0) & (ix1 < W);
        bool vy0 = (iy0 >= 0) & (iy0 < H), vy1 = (iy1 >= 0) & (iy1 < H);
        int cx0 = min(max(ix0, 0), W - 1), cx1 = min(max(ix1, 0), W - 1);
        int cy0 = min(max(iy0, 0), H - 1), cy1 = min(max(iy1, 0), H - 1);
        int   id[4] = {cy0 * W + cx0, cy0 * W + cx1, cy1 * W + cx0, cy1 * W + cx1};
        float wg[4] = {(vx0 && vy0) ? wx0 * wy0 : 0.0f, (vx1 && vy0) ? wx1 * wy0 : 0.0f,
                       (vx0 && vy1) ? wx0 * wy1 : 0.0f, (vx1 && vy1) ? wx1 * wy1 : 0.0f};
        #pragma unroll
        for (int k = 0; k < 4; ++k) {
            sidx[a][k] = __builtin_amdgcn_readfirstlane(id[k]);
            swgt[a][k] = __uint_as_float(__builtin_amdgcn_readfirstlane(__float_as_uint(wg[k])));
        }
    }

    // --- issue ALL 20 corner gathers (one dwordx4 per corner per lane) ---
    const ushort* ib = imgs + (size_t)b * HWs * (2 * C);
    uint4 v[A][4];
    #pragma unroll
    for (int a = 0; a < A; ++a)
        #pragma unroll
        for (int k = 0; k < 4; ++k)
            v[a][k] = *reinterpret_cast<const uint4*>(ib + (size_t)sidx[a][k] * (2 * C) + lane * 8);

    // --- rep: both halves load the same channels (lower: dot; upper: output add) ---
    const float* repp = pf + pn * C + cl * 8;
    float4 r0 = *reinterpret_cast<const float4*>(repp);
    float4 r1 = *reinterpret_cast<const float4*>(repp + 4);
    float rep[8] = {r0.x, r0.y, r0.z, r0.w, r1.x, r1.y, r1.z, r1.w};
    float na2 = 0.f;
    #pragma unroll
    for (int j = 0; j < 8; ++j) na2 += rep[j] * rep[j];
    na2 = reduce32(na2);                       // both halves correct (same rep loaded)
    float na = fmaxf(sqrtf(na2), 1e-8f);

    // --- accumulate weighted corners; per-sample dot / norm ---
    float acc[A][8];
    float sim[A];
    #pragma unroll
    for (int a = 0; a < A; ++a) {
        #pragma unroll
        for (int j = 0; j < 8; ++j) acc[a][j] = 0.f;
        #pragma unroll
        for (int k = 0; k < 4; ++k) {
            float w = swgt[a][k];
            unsigned u0 = v[a][k].x, u1 = v[a][k].y, u2 = v[a][k].z, u3 = v[a][k].w;
            acc[a][0] += w * ulo(u0); acc[a][1] += w * uhi(u0);
            acc[a][2] += w * ulo(u1); acc[a][3] += w * uhi(u1);
            acc[a][4] += w * ulo(u2); acc[a][5] += w * uhi(u2);
            acc[a][6] += w * ulo(u3); acc[a][7] += w * uhi(u3);
        }
        float dt = 0.f, nb2 = 0.f;
        #pragma unroll
        for (int j = 0; j < 8; ++j) {
            dt  += rep[j] * acc[a][j];
            nb2 += acc[a][j] * acc[a][j];
        }
        dt  = reduce32(dt);
        nb2 = reduce32(nb2);
        float dt2  = __shfl_xor(dt, 32);       // lower half's (correct) values
        float nb22 = __shfl_xor(nb2, 32);
        dt  = upper ? dt2 : dt;
        nb2 = upper ? nb22 : nb2;
        sim[a] = dt / (na * fmaxf(sqrtf(nb2), 1e-8f));
    }

    // --- softmax over A (uniform across lanes) ---
    float m = sim[0];
    #pragma unroll
    for (int a = 1; a < A; ++a) m = fmaxf(m, sim[a]);
    float e[A], s = 0.f;
    #pragma unroll
    for (int a = 0; a < A; ++a) { e[a] = __expf(sim[a] - m); s += e[a]; }
    float inv = 1.0f / s;

    // --- upper half holds pe accumulations -> output ---
    if (upper) {
        float o[8];
        #pragma unroll
        for (int j = 0; j < 8; ++j) o[j] = rep[j];
        #pragma unroll
        for (int a = 0; a < A; ++a) {
            float wa = e[a] * inv;
            #pragma unroll
            for (int j = 0; j < 8; ++j) o[j] += wa * acc[a][j];
        }
        float* op = out + pn * C + cl * 8;
        *reinterpret_cast<float4*>(op)     = make_float4(o[0], o[1], o[2], o[3]);
        *reinterpret_cast<float4*>(op + 4) = make_float4(o[4], o[5], o[6], o[7]);
    }
}

extern "C" void kernel_launch(void* const* d_in, const int* in_sizes, int n_in,
                              void* d_out, int out_size, void* d_ws, size_t ws_size,
                              hipStream_t stream) {
    const float* x1  = (const float*)d_in[0];
    const float* pf  = (const float*)d_in[1];
    const float* pts = (const float*)d_in[2];
    const float* pe  = (const float*)d_in[3];
    const float* ao  = (const float*)d_in[4];
    float* out = (float*)d_out;

    __hip_bfloat16* imgs = (__hip_bfloat16*)d_ws;  // [B,HW,2C] bf16 = 64 MiB

    transpose_conv2<<<2 * B * (HWs / 32), 256, 0, stream>>>(x1, pe, imgs);
    soft_align_v3<<<(B * N) / 4, 256, 0, stream>>>((const ushort*)imgs, pf, pts, ao, out);
}